// Round 4
// baseline (207.281 us; speedup 1.0000x reference)
//
#include <hip/hip_runtime.h>

// MoE dense: N=16384, D=256, E=8, H=128.
// R4: stage1+stage2 fused into k_experts — per-block persistent fp32 out-acc,
// loop experts in-kernel: h' = g*relu(x@W1+b1) kept in LDS (never hits HBM),
// y += h'@W2 + g*b2 accumulated in VGPRs. Kills 67MB hw round-trip and the
// K=2080 combine-GEMM (was 49us at 13% MfmaUtil, latency-bound).
// Workspace (~12.3 MB):
//   xb   [16384][288] bf16 @ 0         (col 256 = 1.0 -> gate bias, 257..=0)
//   w1t  [8][256][288] bf16 @ 9437184  (W1^T per expert, col 256 = b1)
//   wg1t [128][288] bf16 @ 10616832    (Wg1^T, col 256 = bg1)
//   w2te [8][256][256] bf16 @ 10690560 (W2^T per expert: [e][d][h])
//   g    [16384][8] f32 @ 11739136

typedef unsigned short USH;
typedef float f32x4 __attribute__((ext_vector_type(4)));
typedef __bf16 bf16x8 __attribute__((ext_vector_type(8)));

#define AS1 __attribute__((address_space(1)))
#define AS3 __attribute__((address_space(3)))

__device__ __forceinline__ USH f2bf(float f) {
  unsigned int u = __float_as_uint(f);
  u += 0x7fffu + ((u >> 16) & 1u);   // RNE
  return (USH)(u >> 16);
}

__device__ __forceinline__ void gl2lds16(const void* g, void* l) {
  __builtin_amdgcn_global_load_lds((AS1 const void*)g, (AS3 void*)l, 16, 0, 0);
}

// ---------------- fused prep kernel ----------------
// blocks [0,2304): xb; [2304,4608): w1t; [4608,4752): wg1t; [4752,6800): w2te

__global__ __launch_bounds__(256) void k_prep_all(
    const float* __restrict__ x,
    const float* __restrict__ Wg1, const float* __restrict__ bg1,
    const float* __restrict__ W1,  const float* __restrict__ b1,
    const float* __restrict__ W2,
    USH* __restrict__ xb, USH* __restrict__ wg1t,
    USH* __restrict__ w1t, USH* __restrict__ w2te) {
  int b = blockIdx.x;
  if (b < 2304) {
    int idx = b * 256 + threadIdx.x;            // 16384*36 threads, 8 cols each
    int n = idx / 36, gc = idx % 36;
    int c0 = gc * 8;
    USH v[8];
#pragma unroll
    for (int k = 0; k < 8; ++k) {
      int c = c0 + k;
      float f = (c < 256) ? x[(size_t)n * 256 + c] : (c == 256 ? 1.0f : 0.0f);
      v[k] = f2bf(f);
    }
    *(uint4*)(xb + (size_t)idx * 8) = *(const uint4*)v;
  } else if (b < 4608) {
    int idx = (b - 2304) * 256 + threadIdx.x;   // 8*256*288
    int e = idx / 73728;
    int rem = idx % 73728;
    int h = rem / 288, c = rem % 288;
    float v = 0.0f;
    if (c < 256) v = W1[(size_t)e * 65536 + (size_t)c * 256 + h];
    else if (c == 256) v = b1[e * 256 + h];
    w1t[idx] = f2bf(v);
  } else if (b < 4752) {
    int idx = (b - 4608) * 256 + threadIdx.x;   // 128*288
    int h = idx / 288, c = idx % 288;
    float v = 0.0f;
    if (c < 256) v = Wg1[(size_t)c * 128 + h];
    else if (c == 256) v = bg1[h];
    wg1t[idx] = f2bf(v);
  } else {
    int idx = (b - 4752) * 256 + threadIdx.x;   // 8*256*256: w2te[e][d][k]=W2[e][k][d]
    int e = idx >> 16;
    int d = (idx >> 8) & 255, k = idx & 255;
    w2te[idx] = f2bf(W2[(size_t)e * 65536 + (size_t)k * 256 + d]);
  }
}

// ---------------- gate: g = softmax(relu(x@Wg1+bg1)@Wg2+bg2) ----------------

__global__ __launch_bounds__(256) void k_gate(const USH* __restrict__ xb,
                                              const USH* __restrict__ wg1t,
                                              const float* __restrict__ wg2,
                                              const float* __restrict__ bg2,
                                              float* __restrict__ g) {
  __shared__ __align__(16) USH As[64 * 32];
  __shared__ __align__(16) USH Bs[128 * 32];
  __shared__ float hg[64 * 129];
  __shared__ float w2s[128 * 8];
  __shared__ float b2s[8];
  __shared__ float lg[64 * 8];

  int tid = threadIdx.x;
  int wave = tid >> 6, lane = tid & 63;
  int quad = lane >> 4, l16 = lane & 15;
  int rowBase = blockIdx.x * 64;

  for (int t = tid; t < 1024; t += 256) w2s[t] = wg2[t];
  if (tid < 8) b2s[tid] = bg2[tid];

  f32x4 acc[8] = {};
  for (int kt = 0; kt < 9; ++kt) {
    int kb = kt * 32;
    {
      int r = tid >> 2, kc = (tid & 3) * 8;
      gl2lds16(xb + (size_t)(rowBase + r) * 288 + kb + kc, As + (size_t)tid * 8);
    }
#pragma unroll
    for (int c = 0; c < 2; ++c) {
      int i = c * 256 + tid;
      int r = i >> 2, kc = (i & 3) * 8;
      gl2lds16(wg1t + (size_t)r * 288 + kb + kc, Bs + (size_t)i * 8);
    }
    __syncthreads();
    bf16x8 av = *(const bf16x8*)(As + (wave * 16 + l16) * 32 + quad * 8);
#pragma unroll
    for (int j = 0; j < 8; ++j) {
      bf16x8 bv = *(const bf16x8*)(Bs + (j * 16 + l16) * 32 + quad * 8);
      acc[j] = __builtin_amdgcn_mfma_f32_16x16x32_bf16(av, bv, acc[j], 0, 0, 0);
    }
    __syncthreads();
  }

#pragma unroll
  for (int j = 0; j < 8; ++j)
#pragma unroll
    for (int r = 0; r < 4; ++r) {
      int row = wave * 16 + quad * 4 + r;
      int col = j * 16 + l16;
      hg[row * 129 + col] = fmaxf(acc[j][r], 0.0f);
    }
  __syncthreads();

  {
    int row = tid >> 2, p = tid & 3;
    float s0 = b2s[p * 2], s1 = b2s[p * 2 + 1];
    for (int k = 0; k < 128; ++k) {
      float h = hg[row * 129 + k];
      s0 += h * w2s[k * 8 + p * 2];
      s1 += h * w2s[k * 8 + p * 2 + 1];
    }
    lg[row * 8 + p * 2] = s0;
    lg[row * 8 + p * 2 + 1] = s1;
  }
  __syncthreads();

  if (tid < 64) {
    float l[8];
    float m = -1e30f;
#pragma unroll
    for (int e = 0; e < 8; ++e) { l[e] = lg[tid * 8 + e]; m = fmaxf(m, l[e]); }
    float s = 0.0f;
#pragma unroll
    for (int e = 0; e < 8; ++e) { l[e] = expf(l[e] - m); s += l[e]; }
    float inv = 1.0f / s;
    size_t grow = rowBase + tid;
#pragma unroll
    for (int e = 0; e < 8; ++e) g[grow * 8 + e] = l[e] * inv;
  }
}

// ---------------- fused experts: out = sum_e g_e*(relu(x@W1_e+b1_e)@W2_e + b2_e) ----
// 256 blocks x 64 rows. Waves split the 256 output cols (64 each).
// LDS 54.5KB -> 2 blocks/CU. acc_out persists in VGPRs across experts.

__global__ __launch_bounds__(256) void k_experts(const USH* __restrict__ xb,
                                                 const USH* __restrict__ w1t,
                                                 const USH* __restrict__ w2te,
                                                 const float* __restrict__ g,
                                                 const float* __restrict__ b2,
                                                 float* __restrict__ out) {
  __shared__ __align__(16) USH Ax[64 * 32];     // 4KB   x K-tile
  __shared__ __align__(16) USH Bs[256 * 32];    // 16KB  W1^T / W2^T K-tile
  __shared__ __align__(16) USH Hs[64 * 264];    // 33KB  h' (pad +8: A-frag reads bank-balanced)
  __shared__ float gs[64];

  int tid = threadIdx.x;
  int wave = tid >> 6, lane = tid & 63;
  int quad = lane >> 4, l16 = lane & 15;
  int rowBase = blockIdx.x * 64;

  f32x4 acc_out[4][4] = {};

  for (int e = 0; e < 8; ++e) {
    if (tid < 64) gs[tid] = g[(size_t)(rowBase + tid) * 8 + e];
    const USH* W1e = w1t + (size_t)e * 256 * 288;
    const USH* W2e = w2te + (size_t)e * 256 * 256;

    // ---- L1: h = x @ W1e^T + b1 (K=288, bias folded) ----
    f32x4 acc_h[4][4] = {};
    for (int kt = 0; kt < 9; ++kt) {
      int kb = kt * 32;
      {
        int r = tid >> 2, kc = (tid & 3) * 8;
        gl2lds16(xb + (size_t)(rowBase + r) * 288 + kb + kc, Ax + (size_t)tid * 8);
      }
#pragma unroll
      for (int c = 0; c < 4; ++c) {
        int i = c * 256 + tid;
        int r = i >> 2, kc = (i & 3) * 8;
        gl2lds16(W1e + (size_t)r * 288 + kb + kc, Bs + (size_t)i * 8);
      }
      __syncthreads();
      bf16x8 av[4], bv[4];
#pragma unroll
      for (int i = 0; i < 4; ++i)
        av[i] = *(const bf16x8*)(Ax + (i * 16 + l16) * 32 + quad * 8);
#pragma unroll
      for (int j = 0; j < 4; ++j)
        bv[j] = *(const bf16x8*)(Bs + (wave * 64 + j * 16 + l16) * 32 + quad * 8);
#pragma unroll
      for (int i = 0; i < 4; ++i)
#pragma unroll
        for (int j = 0; j < 4; ++j)
          acc_h[i][j] = __builtin_amdgcn_mfma_f32_16x16x32_bf16(av[i], bv[j], acc_h[i][j], 0, 0, 0);
      __syncthreads();
    }

    // ---- h' = g * relu(h) -> Hs (bf16, stride 264) ----
#pragma unroll
    for (int i = 0; i < 4; ++i)
#pragma unroll
      for (int r = 0; r < 4; ++r) {
        int row = i * 16 + quad * 4 + r;
        float gg = gs[row];
#pragma unroll
        for (int j = 0; j < 4; ++j) {
          int col = wave * 64 + j * 16 + l16;
          Hs[row * 264 + col] = f2bf(fmaxf(acc_h[i][j][r], 0.0f) * gg);
        }
      }
    __syncthreads();   // Hs visible; Bs free for W2 staging

    // ---- L2: acc_out += h' @ W2e^T (K=256; A straight from LDS) ----
    for (int kt = 0; kt < 8; ++kt) {
      int kb = kt * 32;
#pragma unroll
      for (int c = 0; c < 4; ++c) {
        int i = c * 256 + tid;
        int r = i >> 2, kc = (i & 3) * 8;
        gl2lds16(W2e + (size_t)r * 256 + kb + kc, Bs + (size_t)i * 8);
      }
      __syncthreads();
      bf16x8 av[4], bv[4];
#pragma unroll
      for (int i = 0; i < 4; ++i)
        av[i] = *(const bf16x8*)(Hs + (i * 16 + l16) * 264 + kb + quad * 8);
#pragma unroll
      for (int j = 0; j < 4; ++j)
        bv[j] = *(const bf16x8*)(Bs + (wave * 64 + j * 16 + l16) * 32 + quad * 8);
#pragma unroll
      for (int i = 0; i < 4; ++i)
#pragma unroll
        for (int j = 0; j < 4; ++j)
          acc_out[i][j] = __builtin_amdgcn_mfma_f32_16x16x32_bf16(av[i], bv[j], acc_out[i][j], 0, 0, 0);
      __syncthreads();
    }

    // ---- + g * b2 ----
#pragma unroll
    for (int j = 0; j < 4; ++j) {
      float b2c = b2[e * 256 + wave * 64 + j * 16 + l16];
#pragma unroll
      for (int i = 0; i < 4; ++i)
#pragma unroll
        for (int r = 0; r < 4; ++r)
          acc_out[i][j][r] += gs[i * 16 + quad * 4 + r] * b2c;
    }
    __syncthreads();   // gs rewritten next expert
  }

  // ---- final store ----
#pragma unroll
  for (int i = 0; i < 4; ++i)
#pragma unroll
    for (int r = 0; r < 4; ++r) {
      size_t grow = (size_t)(rowBase + i * 16 + quad * 4 + r);
#pragma unroll
      for (int j = 0; j < 4; ++j)
        out[grow * 256 + wave * 64 + j * 16 + l16] = acc_out[i][j][r];
    }
}

// ---------------- launch ----------------

extern "C" void kernel_launch(void* const* d_in, const int* in_sizes, int n_in,
                              void* d_out, int out_size, void* d_ws, size_t ws_size,
                              hipStream_t stream) {
  const float* x   = (const float*)d_in[0];
  const float* Wg1 = (const float*)d_in[1];
  const float* bg1 = (const float*)d_in[2];
  const float* Wg2 = (const float*)d_in[3];
  const float* bg2 = (const float*)d_in[4];
  const float* W1  = (const float*)d_in[5];
  const float* b1  = (const float*)d_in[6];
  const float* W2  = (const float*)d_in[7];
  const float* b2  = (const float*)d_in[8];
  float* out = (float*)d_out;

  char* ws = (char*)d_ws;
  USH*   xb   = (USH*)(ws);
  USH*   w1t  = (USH*)(ws + 9437184);
  USH*   wg1t = (USH*)(ws + 10616832);
  USH*   w2te = (USH*)(ws + 10690560);
  float* g    = (float*)(ws + 11739136);   // total 12,263,424 B of ws

  hipLaunchKernelGGL(k_prep_all, dim3(6800), dim3(256), 0, stream,
                     x, Wg1, bg1, W1, b1, W2, xb, wg1t, w1t, w2te);
  hipLaunchKernelGGL(k_gate,    dim3(256), dim3(256), 0, stream, xb, wg1t, Wg2, bg2, g);
  hipLaunchKernelGGL(k_experts, dim3(256), dim3(256), 0, stream, xb, w1t, w2te, g, b2, out);
}